// Round 18
// baseline (87.725 us; speedup 1.0000x reference)
//
#include <hip/hip_runtime.h>

#define B 4
#define C 19
#define H 192
#define W 192
#define HW (H * W)
#define NP (B * C)
// 40 / ln(2): exp(-40*x) == exp2(-THETA_LOG2E*x)
#define THETA_LOG2E 57.70780163555855f

#define CSEGS 8
#define CSR 24            // rows per segment (column role)
#define NCOLB (B * C * 3) // 228 column-role blocks
#define NROWB (B * C * H / 8)  // 1824 row-role blocks (8 waves x 1 row)
#define NTHR 512

// bf16 helpers (RNE)
__device__ __forceinline__ unsigned short f2b(float x) {
    unsigned u = __float_as_uint(x);
    u = (u + 0x7FFFu + ((u >> 16) & 1u)) >> 16;
    return (unsigned short)u;
}
__device__ __forceinline__ float b2f(unsigned short h) {
    return __uint_as_float(((unsigned)h) << 16);
}

// ================= per-iteration kernel: col role + row role in one grid =================
// col role : cs_k = Zc + Sc - f_k   (bf16; MODE 2: atomicAdd cs_k*rD into out)
// row role : rs_k = Zr + Sr - 2 f_k (bf16; MODE 2: atomicAdd rs_k*rD into out)
// MODE 0: f = mask; also computes dcol (col c==0) / drow (row c==0), fp32.
// MODE 1: f = (cs+rs)/(dcol+drow-1), writes cs/rs bf16.
// MODE 2: f = (cs+rs)/(dcol+drow-1), accumulates final result into pre-zeroed out.
template<int MODE>
__global__ __launch_bounds__(NTHR) void k_iter(const float* __restrict__ mask,
                                               const float* __restrict__ edge,
                                               const unsigned short* __restrict__ csin,
                                               const unsigned short* __restrict__ rsin,
                                               unsigned short* __restrict__ csout,
                                               unsigned short* __restrict__ rsout,
                                               float* __restrict__ dcol,
                                               float* __restrict__ drow,
                                               float* __restrict__ outg) {
    const int t = threadIdx.x;
    if (blockIdx.x < NCOLB) {
        // ---------------- column role ----------------
        __shared__ float sPf[CSEGS * 64], sQf[CSEGS * 64], sPb[CSEGS * 64], sQb[CSEGS * 64];
        int blk = blockIdx.x;
        int jt = blk % 3, bc = blk / 3, b = bc / C, c = bc % C;
        int jl = t & 63, seg = t >> 6;
        int j = jt * 64 + jl, i0 = seg * CSR;

        const float* ep = edge + ((size_t)b * H + i0) * W + j;
        const size_t fb = ((size_t)bc * H + i0) * W + j;
        const size_t db = ((size_t)b * H + i0) * W + j;

        float dr[CSR + 1], fr[CSR];
        #pragma unroll
        for (int r = 0; r < CSR; ++r) dr[r] = exp2f(-THETA_LOG2E * fmaxf(ep[r * W], 0.f));
        dr[CSR] = (seg < CSEGS - 1) ? exp2f(-THETA_LOG2E * fmaxf(ep[CSR * W], 0.f)) : 0.f;

        if (MODE == 0) {
            #pragma unroll
            for (int r = 0; r < CSR; ++r) fr[r] = mask[fb + r * W];
        } else {
            #pragma unroll
            for (int r = 0; r < CSR; ++r) {
                float cs = b2f(csin[fb + r * W]);
                float rs = b2f(rsin[fb + r * W]);
                float rd = 1.f / (dcol[db + r * W] + drow[db + r * W] - 1.f);
                fr[r] = (cs + rs) * rd;
            }
        }

        float Pf = 1.f, Qf = 0.f, Pb = 1.f, Qb = 0.f;
        #pragma unroll
        for (int r = 0; r < CSR; ++r) { Qf = Qf * dr[r] + fr[r]; Pf *= dr[r]; }
        #pragma unroll
        for (int r = CSR - 1; r >= 0; --r) { Qb = Qb * dr[r + 1] + fr[r]; Pb *= dr[r + 1]; }
        sPf[seg * 64 + jl] = Pf; sQf[seg * 64 + jl] = Qf;
        sPb[seg * 64 + jl] = Pb; sQb[seg * 64 + jl] = Qb;
        __syncthreads();
        if (seg == 0) {          // inclusive prefix transforms
            float P = sPf[jl], Q = sQf[jl];
            for (int s2 = 1; s2 < CSEGS; ++s2) {
                float Pc = sPf[s2 * 64 + jl], Qc = sQf[s2 * 64 + jl];
                Q = Q * Pc + Qc; P = P * Pc;
                sPf[s2 * 64 + jl] = P; sQf[s2 * 64 + jl] = Q;
            }
        } else if (seg == 1) {   // inclusive suffix transforms
            float P = sPb[(CSEGS - 1) * 64 + jl], Q = sQb[(CSEGS - 1) * 64 + jl];
            for (int s2 = CSEGS - 2; s2 >= 0; --s2) {
                float Pc = sPb[s2 * 64 + jl], Qc = sQb[s2 * 64 + jl];
                Q = Q * Pc + Qc; P = P * Pc;
                sPb[s2 * 64 + jl] = P; sQb[s2 * 64 + jl] = Q;
            }
        }
        __syncthreads();
        float z = (seg > 0) ? sQf[(seg - 1) * 64 + jl] : 0.f;
        float s = (seg < CSEGS - 1) ? sQb[(seg + 1) * 64 + jl] : 0.f;
        float zarr[CSR];
        #pragma unroll
        for (int r = 0; r < CSR; ++r) { z = z * dr[r] + fr[r]; zarr[r] = z; }
        if (MODE == 2) {
            #pragma unroll
            for (int r = CSR - 1; r >= 0; --r) {
                s = s * dr[r + 1] + fr[r];
                float rd = 1.f / (dcol[db + r * W] + drow[db + r * W] - 1.f);
                atomicAdd(&outg[fb + r * W], (zarr[r] + s - fr[r]) * rd);
            }
        } else {
            #pragma unroll
            for (int r = CSR - 1; r >= 0; --r) {
                s = s * dr[r + 1] + fr[r];
                csout[fb + r * W] = f2b(zarr[r] + s - fr[r]);   // diagonal counted once
            }
        }

        if (MODE == 0 && c == 0) {
            // unit-f column scan -> dcol = Zu + Su - 1 (fp32)
            float Pf2 = 1.f, Qf2 = 0.f, Pb2 = 1.f, Qb2 = 0.f;
            #pragma unroll
            for (int r = 0; r < CSR; ++r) { Qf2 = Qf2 * dr[r] + 1.f; Pf2 *= dr[r]; }
            #pragma unroll
            for (int r = CSR - 1; r >= 0; --r) { Qb2 = Qb2 * dr[r + 1] + 1.f; Pb2 *= dr[r + 1]; }
            __syncthreads();
            sPf[seg * 64 + jl] = Pf2; sQf[seg * 64 + jl] = Qf2;
            sPb[seg * 64 + jl] = Pb2; sQb[seg * 64 + jl] = Qb2;
            __syncthreads();
            if (seg == 0) {
                float P = sPf[jl], Q = sQf[jl];
                for (int s2 = 1; s2 < CSEGS; ++s2) {
                    float Pc = sPf[s2 * 64 + jl], Qc = sQf[s2 * 64 + jl];
                    Q = Q * Pc + Qc; P = P * Pc;
                    sPf[s2 * 64 + jl] = P; sQf[s2 * 64 + jl] = Q;
                }
            } else if (seg == 1) {
                float P = sPb[(CSEGS - 1) * 64 + jl], Q = sQb[(CSEGS - 1) * 64 + jl];
                for (int s2 = CSEGS - 2; s2 >= 0; --s2) {
                    float Pc = sPb[s2 * 64 + jl], Qc = sQb[s2 * 64 + jl];
                    Q = Q * Pc + Qc; P = P * Pc;
                    sPb[s2 * 64 + jl] = P; sQb[s2 * 64 + jl] = Q;
                }
            }
            __syncthreads();
            float zu = (seg > 0) ? sQf[(seg - 1) * 64 + jl] : 0.f;
            float su = (seg < CSEGS - 1) ? sQb[(seg + 1) * 64 + jl] : 0.f;
            #pragma unroll
            for (int r = 0; r < CSR; ++r) { zu = zu * dr[r] + 1.f; zarr[r] = zu; }
            #pragma unroll
            for (int r = CSR - 1; r >= 0; --r) {
                su = su * dr[r + 1] + 1.f;
                dcol[db + r * W] = zarr[r] + su - 1.f;
            }
        }
    } else {
        // ---------------- row role: one row per wave, 4 elems/lane, 48 active lanes ----------------
        int rblk = blockIdx.x - NCOLB;
        int wave = t >> 6, lane = t & 63;
        int rr = rblk * 8 + wave;              // 0 .. B*C*H-1
        int i = rr % H;
        int c = (rr / H) % C;
        int b = rr / (H * C);
        const size_t rb = ((size_t)(b * C + c) * H + i) * W;
        const size_t db = ((size_t)b * H + i) * W;
        const bool act = lane < 48;
        const int s0 = 4 * (act ? lane : 47);

        float d0 = 0.f, d1 = 0.f, d2 = 0.f, d3 = 0.f;
        float f0 = 0.f, f1 = 0.f, f2v = 0.f, f3 = 0.f;
        float rd0 = 0.f, rd1 = 0.f, rd2 = 0.f, rd3 = 0.f;
        if (act) {
            float4 ev = *(const float4*)&edge[db + s0];
            d0 = exp2f(-THETA_LOG2E * fmaxf(ev.x, 0.f));
            d1 = exp2f(-THETA_LOG2E * fmaxf(ev.y, 0.f));
            d2 = exp2f(-THETA_LOG2E * fmaxf(ev.z, 0.f));
            d3 = exp2f(-THETA_LOG2E * fmaxf(ev.w, 0.f));
            if (MODE == 0) {
                float4 mv = *(const float4*)&mask[rb + s0];
                f0 = mv.x; f1 = mv.y; f2v = mv.z; f3 = mv.w;
            } else {
                float4 dc = *(const float4*)&dcol[db + s0];
                float4 dw = *(const float4*)&drow[db + s0];
                rd0 = 1.f / (dc.x + dw.x - 1.f);
                rd1 = 1.f / (dc.y + dw.y - 1.f);
                rd2 = 1.f / (dc.z + dw.z - 1.f);
                rd3 = 1.f / (dc.w + dw.w - 1.f);
                ushort4 cu = *(const ushort4*)&csin[rb + s0];
                ushort4 ru = *(const ushort4*)&rsin[rb + s0];
                f0  = (b2f(cu.x) + b2f(ru.x)) * rd0;
                f1  = (b2f(cu.y) + b2f(ru.y)) * rd1;
                f2v = (b2f(cu.z) + b2f(ru.z)) * rd2;
                f3  = (b2f(cu.w) + b2f(ru.w)) * rd3;
            }
        }
        float d4 = __shfl_down(d0, 1);
        if (lane >= 47) d4 = 0.f;

        // ---- forward scan: Z[s] = d[s]*Z[s-1] + f[s] ----
        float P = 1.f, Q = 0.f;
        if (act) {
            P = d0 * d1 * d2 * d3;
            Q = ((f0 * d1 + f1) * d2 + f2v) * d3 + f3;
        }
        #pragma unroll
        for (int off = 1; off < 64; off <<= 1) {
            float Pp = __shfl_up(P, off);
            float Qp = __shfl_up(Q, off);
            if (lane >= off) { Q = Qp * P + Q; P = Pp * P; }
        }
        float zin = __shfl_up(Q, 1);
        if (lane == 0) zin = 0.f;
        float zA = zin * d0 + f0;
        float zB = zA * d1 + f1;
        float zC = zB * d2 + f2v;
        float zD = zC * d3 + f3;

        // ---- backward scan: Sf[s] = d[s+1]*Sf[s+1] + f[s]; lanes >=48 carry identity (1,0) ----
        float Pb = 1.f, Qb = 0.f;
        if (act) {
            Pb = d4 * d3 * d2 * d1;
            Qb = ((f3 * d3 + f2v) * d2 + f1) * d1 + f0;
        }
        #pragma unroll
        for (int off = 1; off < 64; off <<= 1) {
            float Pp = __shfl_down(Pb, off);
            float Qp = __shfl_down(Qb, off);
            if (lane < 64 - off) { Qb = Qp * Pb + Qb; Pb = Pp * Pb; }
        }
        float sin_ = __shfl_down(Qb, 1);
        if (lane == 63) sin_ = 0.f;
        float sD = sin_ * d4 + f3;
        float sC = sD * d3 + f2v;
        float sB = sC * d2 + f1;
        float sA = sB * d1 + f0;

        if (act) {
            if (MODE == 2) {
                atomicAdd(&outg[rb + s0],     (zA + sA - 2.f * f0)  * rd0);
                atomicAdd(&outg[rb + s0 + 1], (zB + sB - 2.f * f1)  * rd1);
                atomicAdd(&outg[rb + s0 + 2], (zC + sC - 2.f * f2v) * rd2);
                atomicAdd(&outg[rb + s0 + 3], (zD + sD - 2.f * f3)  * rd3);
            } else {
                ushort4 o;
                o.x = f2b(zA + sA - 2.f * f0);
                o.y = f2b(zB + sB - 2.f * f1);
                o.z = f2b(zC + sC - 2.f * f2v);
                o.w = f2b(zD + sD - 2.f * f3);
                *(ushort4*)&rsout[rb + s0] = o;
            }
        }

        if (MODE == 0 && c == 0) {
            // unit-f row scan -> drow = Zu + Su - 1 (fp32)
            float Pu = 1.f, Qu = 0.f;
            if (act) {
                Pu = d0 * d1 * d2 * d3;
                Qu = ((d1 + 1.f) * d2 + 1.f) * d3 + 1.f;
            }
            #pragma unroll
            for (int off = 1; off < 64; off <<= 1) {
                float Pp = __shfl_up(Pu, off);
                float Qp = __shfl_up(Qu, off);
                if (lane >= off) { Qu = Qp * Pu + Qu; Pu = Pp * Pu; }
            }
            float zuin = __shfl_up(Qu, 1);
            if (lane == 0) zuin = 0.f;
            float zuA = zuin * d0 + 1.f;
            float zuB = zuA * d1 + 1.f;
            float zuC = zuB * d2 + 1.f;
            float zuD = zuC * d3 + 1.f;

            float Pub = 1.f, Qub = 0.f;
            if (act) {
                Pub = d4 * d3 * d2 * d1;
                Qub = ((d3 + 1.f) * d2 + 1.f) * d1 + 1.f;
            }
            #pragma unroll
            for (int off = 1; off < 64; off <<= 1) {
                float Pp = __shfl_down(Pub, off);
                float Qp = __shfl_down(Qub, off);
                if (lane < 64 - off) { Qub = Qp * Pub + Qub; Pub = Pp * Pub; }
            }
            float suin = __shfl_down(Qub, 1);
            if (lane == 63) suin = 0.f;
            float suD = suin * d4 + 1.f;
            float suC = suD * d3 + 1.f;
            float suB = suC * d2 + 1.f;
            float suA = suB * d1 + 1.f;

            if (act) {
                float4 o;
                o.x = zuA + suA - 1.f;
                o.y = zuB + suB - 1.f;
                o.z = zuC + suC - 1.f;
                o.w = zuD + suD - 1.f;
                *(float4*)&drow[db + s0] = o;
            }
        }
    }
}

extern "C" void kernel_launch(void* const* d_in, const int* in_sizes, int n_in,
                              void* d_out, int out_size, void* d_ws, size_t ws_size,
                              hipStream_t stream) {
    const float* mask = (const float*)d_in[0];
    const float* edge = (const float*)d_in[1];
    float* out = (float*)d_out;

    float* dcol = (float*)d_ws;                         // [B,H,W] fp32
    float* drow = dcol + (size_t)B * HW;                // [B,H,W] fp32
    unsigned short* csA = (unsigned short*)(drow + (size_t)B * HW);
    unsigned short* rsA = csA + (size_t)NP * HW;        // bf16 [NP,H,W] each
    unsigned short* csB = rsA + (size_t)NP * HW;
    unsigned short* rsB = csB + (size_t)NP * HW;

    const int grid = NCOLB + NROWB;   // 2052

    // pre-zero out: final iteration accumulates exactly 2 atomic adds per element (deterministic)
    hipMemsetAsync(out, 0, (size_t)NP * HW * sizeof(float), stream);
    // L1: f0 = mask -> csA, rsA (+ dcol, drow)
    k_iter<0><<<grid, NTHR, 0, stream>>>(mask, edge, nullptr, nullptr, csA, rsA, dcol, drow, nullptr);
    // L2: fold A -> B
    k_iter<1><<<grid, NTHR, 0, stream>>>(nullptr, edge, csA, rsA, csB, rsB, dcol, drow, nullptr);
    // L3: fold B, accumulate final result into out
    k_iter<2><<<grid, NTHR, 0, stream>>>(nullptr, edge, csB, rsB, nullptr, nullptr, dcol, drow, out);
}

// Round 19
// 51.289 us; speedup vs baseline: 1.7104x; 1.7104x over previous
//
#include <hip/hip_runtime.h>

#define B 4
#define C 19
#define H 192
#define W 192
#define HW (H * W)
#define NP (B * C)
// 40 / ln(2): exp(-40*x) == exp2(-THETA_LOG2E*x)
#define THETA_LOG2E 57.70780163555855f

#define CSEGS 8
#define CSR 24            // rows per segment (column role)
#define NCOLB (B * C * 3) // 228 column-role blocks
#define NROWB (B * C * H / 8)  // 1824 row-role blocks (8 waves x 1 row)
#define NTHR 512

// bf16 helpers (RNE)
__device__ __forceinline__ unsigned short f2b(float x) {
    unsigned u = __float_as_uint(x);
    u = (u + 0x7FFFu + ((u >> 16) & 1u)) >> 16;
    return (unsigned short)u;
}
__device__ __forceinline__ float b2f(unsigned short h) {
    return __uint_as_float(((unsigned)h) << 16);
}

// ================= per-iteration kernel: col role + row role in one grid =================
// col role : cs_k = Zc + Sc - f_k   (bf16 out)
// row role : rs_k = Zr + Sr - 2 f_k (bf16 out)
// MODE 0: f = mask; also computes dcol (col c==0) / drow (row c==0), fp32.
// MODE >0: f = (cs+rs)/(dcol+drow-1) folded on the fly.
template<int MODE>
__global__ __launch_bounds__(NTHR) void k_iter(const float* __restrict__ mask,
                                               const float* __restrict__ edge,
                                               const unsigned short* __restrict__ csin,
                                               const unsigned short* __restrict__ rsin,
                                               unsigned short* __restrict__ csout,
                                               unsigned short* __restrict__ rsout,
                                               float* __restrict__ dcol,
                                               float* __restrict__ drow) {
    const int t = threadIdx.x;
    if (blockIdx.x < NCOLB) {
        // ---------------- column role ----------------
        __shared__ float sPf[CSEGS * 64], sQf[CSEGS * 64], sPb[CSEGS * 64], sQb[CSEGS * 64];
        int blk = blockIdx.x;
        int jt = blk % 3, bc = blk / 3, b = bc / C, c = bc % C;
        int jl = t & 63, seg = t >> 6;
        int j = jt * 64 + jl, i0 = seg * CSR;

        const float* ep = edge + ((size_t)b * H + i0) * W + j;
        const size_t fb = ((size_t)bc * H + i0) * W + j;
        const size_t db = ((size_t)b * H + i0) * W + j;

        float dr[CSR + 1], fr[CSR];
        #pragma unroll
        for (int r = 0; r < CSR; ++r) dr[r] = exp2f(-THETA_LOG2E * fmaxf(ep[r * W], 0.f));
        dr[CSR] = (seg < CSEGS - 1) ? exp2f(-THETA_LOG2E * fmaxf(ep[CSR * W], 0.f)) : 0.f;

        if (MODE == 0) {
            #pragma unroll
            for (int r = 0; r < CSR; ++r) fr[r] = mask[fb + r * W];
        } else {
            #pragma unroll
            for (int r = 0; r < CSR; ++r) {
                float cs = b2f(csin[fb + r * W]);
                float rs = b2f(rsin[fb + r * W]);
                float rd = 1.f / (dcol[db + r * W] + drow[db + r * W] - 1.f);
                fr[r] = (cs + rs) * rd;
            }
        }

        float Pf = 1.f, Qf = 0.f, Pb = 1.f, Qb = 0.f;
        #pragma unroll
        for (int r = 0; r < CSR; ++r) { Qf = Qf * dr[r] + fr[r]; Pf *= dr[r]; }
        #pragma unroll
        for (int r = CSR - 1; r >= 0; --r) { Qb = Qb * dr[r + 1] + fr[r]; Pb *= dr[r + 1]; }
        sPf[seg * 64 + jl] = Pf; sQf[seg * 64 + jl] = Qf;
        sPb[seg * 64 + jl] = Pb; sQb[seg * 64 + jl] = Qb;
        __syncthreads();
        if (seg == 0) {          // inclusive prefix transforms
            float P = sPf[jl], Q = sQf[jl];
            for (int s2 = 1; s2 < CSEGS; ++s2) {
                float Pc = sPf[s2 * 64 + jl], Qc = sQf[s2 * 64 + jl];
                Q = Q * Pc + Qc; P = P * Pc;
                sPf[s2 * 64 + jl] = P; sQf[s2 * 64 + jl] = Q;
            }
        } else if (seg == 1) {   // inclusive suffix transforms
            float P = sPb[(CSEGS - 1) * 64 + jl], Q = sQb[(CSEGS - 1) * 64 + jl];
            for (int s2 = CSEGS - 2; s2 >= 0; --s2) {
                float Pc = sPb[s2 * 64 + jl], Qc = sQb[s2 * 64 + jl];
                Q = Q * Pc + Qc; P = P * Pc;
                sPb[s2 * 64 + jl] = P; sQb[s2 * 64 + jl] = Q;
            }
        }
        __syncthreads();
        float z = (seg > 0) ? sQf[(seg - 1) * 64 + jl] : 0.f;
        float s = (seg < CSEGS - 1) ? sQb[(seg + 1) * 64 + jl] : 0.f;
        float zarr[CSR];
        #pragma unroll
        for (int r = 0; r < CSR; ++r) { z = z * dr[r] + fr[r]; zarr[r] = z; }
        #pragma unroll
        for (int r = CSR - 1; r >= 0; --r) {
            s = s * dr[r + 1] + fr[r];
            csout[fb + r * W] = f2b(zarr[r] + s - fr[r]);   // diagonal counted once
        }

        if (MODE == 0 && c == 0) {
            // unit-f column scan -> dcol = Zu + Su - 1 (fp32)
            float Pf2 = 1.f, Qf2 = 0.f, Pb2 = 1.f, Qb2 = 0.f;
            #pragma unroll
            for (int r = 0; r < CSR; ++r) { Qf2 = Qf2 * dr[r] + 1.f; Pf2 *= dr[r]; }
            #pragma unroll
            for (int r = CSR - 1; r >= 0; --r) { Qb2 = Qb2 * dr[r + 1] + 1.f; Pb2 *= dr[r + 1]; }
            __syncthreads();
            sPf[seg * 64 + jl] = Pf2; sQf[seg * 64 + jl] = Qf2;
            sPb[seg * 64 + jl] = Pb2; sQb[seg * 64 + jl] = Qb2;
            __syncthreads();
            if (seg == 0) {
                float P = sPf[jl], Q = sQf[jl];
                for (int s2 = 1; s2 < CSEGS; ++s2) {
                    float Pc = sPf[s2 * 64 + jl], Qc = sQf[s2 * 64 + jl];
                    Q = Q * Pc + Qc; P = P * Pc;
                    sPf[s2 * 64 + jl] = P; sQf[s2 * 64 + jl] = Q;
                }
            } else if (seg == 1) {
                float P = sPb[(CSEGS - 1) * 64 + jl], Q = sQb[(CSEGS - 1) * 64 + jl];
                for (int s2 = CSEGS - 2; s2 >= 0; --s2) {
                    float Pc = sPb[s2 * 64 + jl], Qc = sQb[s2 * 64 + jl];
                    Q = Q * Pc + Qc; P = P * Pc;
                    sPb[s2 * 64 + jl] = P; sQb[s2 * 64 + jl] = Q;
                }
            }
            __syncthreads();
            float zu = (seg > 0) ? sQf[(seg - 1) * 64 + jl] : 0.f;
            float su = (seg < CSEGS - 1) ? sQb[(seg + 1) * 64 + jl] : 0.f;
            #pragma unroll
            for (int r = 0; r < CSR; ++r) { zu = zu * dr[r] + 1.f; zarr[r] = zu; }
            #pragma unroll
            for (int r = CSR - 1; r >= 0; --r) {
                su = su * dr[r + 1] + 1.f;
                dcol[db + r * W] = zarr[r] + su - 1.f;
            }
        }
    } else {
        // ---------------- row role: one row per wave, 4 elems/lane, 48 active lanes ----------------
        int rblk = blockIdx.x - NCOLB;
        int wave = t >> 6, lane = t & 63;
        int rr = rblk * 8 + wave;              // 0 .. B*C*H-1
        int i = rr % H;
        int c = (rr / H) % C;
        int b = rr / (H * C);
        const size_t rb = ((size_t)(b * C + c) * H + i) * W;
        const size_t db = ((size_t)b * H + i) * W;
        const bool act = lane < 48;
        const int s0 = 4 * (act ? lane : 47);

        float d0 = 0.f, d1 = 0.f, d2 = 0.f, d3 = 0.f;
        float f0 = 0.f, f1 = 0.f, f2v = 0.f, f3 = 0.f;
        if (act) {
            float4 ev = *(const float4*)&edge[db + s0];
            d0 = exp2f(-THETA_LOG2E * fmaxf(ev.x, 0.f));
            d1 = exp2f(-THETA_LOG2E * fmaxf(ev.y, 0.f));
            d2 = exp2f(-THETA_LOG2E * fmaxf(ev.z, 0.f));
            d3 = exp2f(-THETA_LOG2E * fmaxf(ev.w, 0.f));
            if (MODE == 0) {
                float4 mv = *(const float4*)&mask[rb + s0];
                f0 = mv.x; f1 = mv.y; f2v = mv.z; f3 = mv.w;
            } else {
                float4 dc = *(const float4*)&dcol[db + s0];
                float4 dw = *(const float4*)&drow[db + s0];
                ushort4 cu = *(const ushort4*)&csin[rb + s0];
                ushort4 ru = *(const ushort4*)&rsin[rb + s0];
                f0  = (b2f(cu.x) + b2f(ru.x)) / (dc.x + dw.x - 1.f);
                f1  = (b2f(cu.y) + b2f(ru.y)) / (dc.y + dw.y - 1.f);
                f2v = (b2f(cu.z) + b2f(ru.z)) / (dc.z + dw.z - 1.f);
                f3  = (b2f(cu.w) + b2f(ru.w)) / (dc.w + dw.w - 1.f);
            }
        }
        float d4 = __shfl_down(d0, 1);
        if (lane >= 47) d4 = 0.f;

        // ---- forward scan: Z[s] = d[s]*Z[s-1] + f[s] ----
        float P = 1.f, Q = 0.f;
        if (act) {
            P = d0 * d1 * d2 * d3;
            Q = ((f0 * d1 + f1) * d2 + f2v) * d3 + f3;
        }
        #pragma unroll
        for (int off = 1; off < 64; off <<= 1) {
            float Pp = __shfl_up(P, off);
            float Qp = __shfl_up(Q, off);
            if (lane >= off) { Q = Qp * P + Q; P = Pp * P; }
        }
        float zin = __shfl_up(Q, 1);
        if (lane == 0) zin = 0.f;
        float zA = zin * d0 + f0;
        float zB = zA * d1 + f1;
        float zC = zB * d2 + f2v;
        float zD = zC * d3 + f3;

        // ---- backward scan: Sf[s] = d[s+1]*Sf[s+1] + f[s]; lanes >=48 carry identity (1,0) ----
        float Pb = 1.f, Qb = 0.f;
        if (act) {
            Pb = d4 * d3 * d2 * d1;
            Qb = ((f3 * d3 + f2v) * d2 + f1) * d1 + f0;
        }
        #pragma unroll
        for (int off = 1; off < 64; off <<= 1) {
            float Pp = __shfl_down(Pb, off);
            float Qp = __shfl_down(Qb, off);
            if (lane < 64 - off) { Qb = Qp * Pb + Qb; Pb = Pp * Pb; }
        }
        float sin_ = __shfl_down(Qb, 1);
        if (lane == 63) sin_ = 0.f;
        float sD = sin_ * d4 + f3;
        float sC = sD * d3 + f2v;
        float sB = sC * d2 + f1;
        float sA = sB * d1 + f0;

        if (act) {
            ushort4 o;
            o.x = f2b(zA + sA - 2.f * f0);
            o.y = f2b(zB + sB - 2.f * f1);
            o.z = f2b(zC + sC - 2.f * f2v);
            o.w = f2b(zD + sD - 2.f * f3);
            *(ushort4*)&rsout[rb + s0] = o;
        }

        if (MODE == 0 && c == 0) {
            // unit-f row scan -> drow = Zu + Su - 1 (fp32)
            float Pu = 1.f, Qu = 0.f;
            if (act) {
                Pu = d0 * d1 * d2 * d3;
                Qu = ((d1 + 1.f) * d2 + 1.f) * d3 + 1.f;
            }
            #pragma unroll
            for (int off = 1; off < 64; off <<= 1) {
                float Pp = __shfl_up(Pu, off);
                float Qp = __shfl_up(Qu, off);
                if (lane >= off) { Qu = Qp * Pu + Qu; Pu = Pp * Pu; }
            }
            float zuin = __shfl_up(Qu, 1);
            if (lane == 0) zuin = 0.f;
            float zuA = zuin * d0 + 1.f;
            float zuB = zuA * d1 + 1.f;
            float zuC = zuB * d2 + 1.f;
            float zuD = zuC * d3 + 1.f;

            float Pub = 1.f, Qub = 0.f;
            if (act) {
                Pub = d4 * d3 * d2 * d1;
                Qub = ((d3 + 1.f) * d2 + 1.f) * d1 + 1.f;
            }
            #pragma unroll
            for (int off = 1; off < 64; off <<= 1) {
                float Pp = __shfl_down(Pub, off);
                float Qp = __shfl_down(Qub, off);
                if (lane < 64 - off) { Qub = Qp * Pub + Qub; Pub = Pp * Pub; }
            }
            float suin = __shfl_down(Qub, 1);
            if (lane == 63) suin = 0.f;
            float suD = suin * d4 + 1.f;
            float suC = suD * d3 + 1.f;
            float suB = suC * d2 + 1.f;
            float suA = suB * d1 + 1.f;

            if (act) {
                float4 o;
                o.x = zuA + suA - 1.f;
                o.y = zuB + suB - 1.f;
                o.z = zuC + suC - 1.f;
                o.w = zuD + suD - 1.f;
                *(float4*)&drow[db + s0] = o;
            }
        }
    }
}

// ================= final combine: out = (cs + rs) / (dcol + drow - 1) =================
__global__ __launch_bounds__(256) void k_comb(const unsigned short* __restrict__ cs,
                                              const unsigned short* __restrict__ rs,
                                              const float* __restrict__ dcol,
                                              const float* __restrict__ drow,
                                              float* __restrict__ out) {
    int idx4 = (blockIdx.x * 256 + threadIdx.x) * 4;    // NP*HW / 4 threads
    int p = idx4 / HW;
    int rem = idx4 - p * HW;
    int b = p / C;
    size_t db = (size_t)b * HW + rem;
    uint2 csu = *(const uint2*)(cs + idx4);
    uint2 rsu = *(const uint2*)(rs + idx4);
    float4 dc = *(const float4*)(dcol + db);
    float4 dw = *(const float4*)(drow + db);
    float4 o;
    o.x = (b2f((unsigned short)(csu.x & 0xffff)) + b2f((unsigned short)(rsu.x & 0xffff))) / (dc.x + dw.x - 1.f);
    o.y = (b2f((unsigned short)(csu.x >> 16))    + b2f((unsigned short)(rsu.x >> 16)))    / (dc.y + dw.y - 1.f);
    o.z = (b2f((unsigned short)(csu.y & 0xffff)) + b2f((unsigned short)(rsu.y & 0xffff))) / (dc.z + dw.z - 1.f);
    o.w = (b2f((unsigned short)(csu.y >> 16))    + b2f((unsigned short)(rsu.y >> 16)))    / (dc.w + dw.w - 1.f);
    *(float4*)(out + idx4) = o;
}

extern "C" void kernel_launch(void* const* d_in, const int* in_sizes, int n_in,
                              void* d_out, int out_size, void* d_ws, size_t ws_size,
                              hipStream_t stream) {
    const float* mask = (const float*)d_in[0];
    const float* edge = (const float*)d_in[1];
    float* out = (float*)d_out;

    float* dcol = (float*)d_ws;                         // [B,H,W] fp32
    float* drow = dcol + (size_t)B * HW;                // [B,H,W] fp32
    unsigned short* csA = (unsigned short*)(drow + (size_t)B * HW);
    unsigned short* rsA = csA + (size_t)NP * HW;        // bf16 [NP,H,W] each
    unsigned short* csB = rsA + (size_t)NP * HW;
    unsigned short* rsB = csB + (size_t)NP * HW;

    const int grid = NCOLB + NROWB;   // 2052

    // L1: f0 = mask -> csA, rsA (+ dcol, drow)
    k_iter<0><<<grid, NTHR, 0, stream>>>(mask, edge, nullptr, nullptr, csA, rsA, dcol, drow);
    // L2: fold A -> B
    k_iter<1><<<grid, NTHR, 0, stream>>>(nullptr, edge, csA, rsA, csB, rsB, dcol, drow);
    // L3: fold B -> A
    k_iter<2><<<grid, NTHR, 0, stream>>>(nullptr, edge, csB, rsB, csA, rsA, dcol, drow);
    // final combine -> out
    k_comb<<<(NP * HW) / (4 * 256), 256, 0, stream>>>(csA, rsA, dcol, drow, out);
}

// Round 20
// 47.855 us; speedup vs baseline: 1.8331x; 1.0718x over previous
//
#include <hip/hip_runtime.h>

#define B 4
#define C 19
#define H 192
#define W 192
#define HW (H * W)
#define NP (B * C)
// 40 / ln(2): exp(-40*x) == exp2(-THETA_LOG2E*x)
#define THETA_LOG2E 57.70780163555855f

#define CSEGS 8
#define CSR 24            // rows per segment (column role)
#define NCOLB (B * C * 3) // 228 column-role blocks
#define NROWB (B * C * H / 8)  // 1824 row-role blocks (8 waves x 1 row)
#define NTHR 512

// bf16 helpers (RNE)
__device__ __forceinline__ unsigned short f2b(float x) {
    unsigned u = __float_as_uint(x);
    u = (u + 0x7FFFu + ((u >> 16) & 1u)) >> 16;
    return (unsigned short)u;
}
__device__ __forceinline__ float b2f(unsigned short h) {
    return __uint_as_float(((unsigned)h) << 16);
}

// ---------------- column role body (proven R11/R19): cs_k = Zc + Sc - f_k ----------------
// MODE 0: f = mask, c==0 blocks also write dcol.  MODE 1: f = (cs+rs)/(dcol+drow-1).
template<int MODE>
__device__ __forceinline__ void col_body(int blk, int t,
                                         const float* __restrict__ mask,
                                         const float* __restrict__ edge,
                                         const unsigned short* __restrict__ csin,
                                         const unsigned short* __restrict__ rsin,
                                         unsigned short* __restrict__ csout,
                                         float* __restrict__ dcol,
                                         const float* __restrict__ drow) {
    __shared__ float sPf[CSEGS * 64], sQf[CSEGS * 64], sPb[CSEGS * 64], sQb[CSEGS * 64];
    int jt = blk % 3, bc = blk / 3, b = bc / C, c = bc % C;
    int jl = t & 63, seg = t >> 6;
    int j = jt * 64 + jl, i0 = seg * CSR;

    const float* ep = edge + ((size_t)b * H + i0) * W + j;
    const size_t fb = ((size_t)bc * H + i0) * W + j;
    const size_t db = ((size_t)b * H + i0) * W + j;

    float dr[CSR + 1], fr[CSR];
    #pragma unroll
    for (int r = 0; r < CSR; ++r) dr[r] = exp2f(-THETA_LOG2E * fmaxf(ep[r * W], 0.f));
    dr[CSR] = (seg < CSEGS - 1) ? exp2f(-THETA_LOG2E * fmaxf(ep[CSR * W], 0.f)) : 0.f;

    if (MODE == 0) {
        #pragma unroll
        for (int r = 0; r < CSR; ++r) fr[r] = mask[fb + r * W];
    } else {
        #pragma unroll
        for (int r = 0; r < CSR; ++r) {
            float cs = b2f(csin[fb + r * W]);
            float rs = b2f(rsin[fb + r * W]);
            float rd = 1.f / (dcol[db + r * W] + drow[db + r * W] - 1.f);
            fr[r] = (cs + rs) * rd;
        }
    }

    float Pf = 1.f, Qf = 0.f, Pb = 1.f, Qb = 0.f;
    #pragma unroll
    for (int r = 0; r < CSR; ++r) { Qf = Qf * dr[r] + fr[r]; Pf *= dr[r]; }
    #pragma unroll
    for (int r = CSR - 1; r >= 0; --r) { Qb = Qb * dr[r + 1] + fr[r]; Pb *= dr[r + 1]; }
    sPf[seg * 64 + jl] = Pf; sQf[seg * 64 + jl] = Qf;
    sPb[seg * 64 + jl] = Pb; sQb[seg * 64 + jl] = Qb;
    __syncthreads();
    if (seg == 0) {          // inclusive prefix transforms
        float P = sPf[jl], Q = sQf[jl];
        for (int s2 = 1; s2 < CSEGS; ++s2) {
            float Pc = sPf[s2 * 64 + jl], Qc = sQf[s2 * 64 + jl];
            Q = Q * Pc + Qc; P = P * Pc;
            sPf[s2 * 64 + jl] = P; sQf[s2 * 64 + jl] = Q;
        }
    } else if (seg == 1) {   // inclusive suffix transforms
        float P = sPb[(CSEGS - 1) * 64 + jl], Q = sQb[(CSEGS - 1) * 64 + jl];
        for (int s2 = CSEGS - 2; s2 >= 0; --s2) {
            float Pc = sPb[s2 * 64 + jl], Qc = sQb[s2 * 64 + jl];
            Q = Q * Pc + Qc; P = P * Pc;
            sPb[s2 * 64 + jl] = P; sQb[s2 * 64 + jl] = Q;
        }
    }
    __syncthreads();
    float z = (seg > 0) ? sQf[(seg - 1) * 64 + jl] : 0.f;
    float s = (seg < CSEGS - 1) ? sQb[(seg + 1) * 64 + jl] : 0.f;
    float zarr[CSR];
    #pragma unroll
    for (int r = 0; r < CSR; ++r) { z = z * dr[r] + fr[r]; zarr[r] = z; }
    #pragma unroll
    for (int r = CSR - 1; r >= 0; --r) {
        s = s * dr[r + 1] + fr[r];
        csout[fb + r * W] = f2b(zarr[r] + s - fr[r]);   // diagonal counted once
    }

    if (MODE == 0 && c == 0) {
        // unit-f column scan -> dcol = Zu + Su - 1 (fp32)
        float Pf2 = 1.f, Qf2 = 0.f, Pb2 = 1.f, Qb2 = 0.f;
        #pragma unroll
        for (int r = 0; r < CSR; ++r) { Qf2 = Qf2 * dr[r] + 1.f; Pf2 *= dr[r]; }
        #pragma unroll
        for (int r = CSR - 1; r >= 0; --r) { Qb2 = Qb2 * dr[r + 1] + 1.f; Pb2 *= dr[r + 1]; }
        __syncthreads();
        sPf[seg * 64 + jl] = Pf2; sQf[seg * 64 + jl] = Qf2;
        sPb[seg * 64 + jl] = Pb2; sQb[seg * 64 + jl] = Qb2;
        __syncthreads();
        if (seg == 0) {
            float P = sPf[jl], Q = sQf[jl];
            for (int s2 = 1; s2 < CSEGS; ++s2) {
                float Pc = sPf[s2 * 64 + jl], Qc = sQf[s2 * 64 + jl];
                Q = Q * Pc + Qc; P = P * Pc;
                sPf[s2 * 64 + jl] = P; sQf[s2 * 64 + jl] = Q;
            }
        } else if (seg == 1) {
            float P = sPb[(CSEGS - 1) * 64 + jl], Q = sQb[(CSEGS - 1) * 64 + jl];
            for (int s2 = CSEGS - 2; s2 >= 0; --s2) {
                float Pc = sPb[s2 * 64 + jl], Qc = sQb[s2 * 64 + jl];
                Q = Q * Pc + Qc; P = P * Pc;
                sPb[s2 * 64 + jl] = P; sQb[s2 * 64 + jl] = Q;
            }
        }
        __syncthreads();
        float zu = (seg > 0) ? sQf[(seg - 1) * 64 + jl] : 0.f;
        float su = (seg < CSEGS - 1) ? sQb[(seg + 1) * 64 + jl] : 0.f;
        #pragma unroll
        for (int r = 0; r < CSR; ++r) { zu = zu * dr[r] + 1.f; zarr[r] = zu; }
        #pragma unroll
        for (int r = CSR - 1; r >= 0; --r) {
            su = su * dr[r + 1] + 1.f;
            dcol[db + r * W] = zarr[r] + su - 1.f;
        }
    }
}

// ---------------- row role body (proven R18/R19): 4 elems/lane, 48 active lanes ----------------
// MODE 0: f = mask, c==0 waves also write drow; stores rs bf16.
// MODE 1: fold, stores rs bf16.
// MODE 2 (FINAL): fold, reads cs2 (csfin) and writes out = (cs2 + rs2)*rD fp32 directly.
template<int MODE>
__device__ __forceinline__ void row_body(int rr, int lane,
                                         const float* __restrict__ mask,
                                         const float* __restrict__ edge,
                                         const unsigned short* __restrict__ csin,
                                         const unsigned short* __restrict__ rsin,
                                         unsigned short* __restrict__ rsout,
                                         const unsigned short* __restrict__ csfin,
                                         const float* __restrict__ dcol,
                                         float* __restrict__ drow,
                                         float* __restrict__ outg) {
    int i = rr % H;
    int c = (rr / H) % C;
    int b = rr / (H * C);
    const size_t rb = ((size_t)(b * C + c) * H + i) * W;
    const size_t db = ((size_t)b * H + i) * W;
    const bool act = lane < 48;
    const int s0 = 4 * (act ? lane : 47);

    float d0 = 0.f, d1 = 0.f, d2 = 0.f, d3 = 0.f;
    float f0 = 0.f, f1 = 0.f, f2v = 0.f, f3 = 0.f;
    float rd0 = 0.f, rd1 = 0.f, rd2 = 0.f, rd3 = 0.f;
    if (act) {
        float4 ev = *(const float4*)&edge[db + s0];
        d0 = exp2f(-THETA_LOG2E * fmaxf(ev.x, 0.f));
        d1 = exp2f(-THETA_LOG2E * fmaxf(ev.y, 0.f));
        d2 = exp2f(-THETA_LOG2E * fmaxf(ev.z, 0.f));
        d3 = exp2f(-THETA_LOG2E * fmaxf(ev.w, 0.f));
        if (MODE == 0) {
            float4 mv = *(const float4*)&mask[rb + s0];
            f0 = mv.x; f1 = mv.y; f2v = mv.z; f3 = mv.w;
        } else {
            float4 dc = *(const float4*)&dcol[db + s0];
            float4 dw = *(const float4*)&drow[db + s0];
            rd0 = 1.f / (dc.x + dw.x - 1.f);
            rd1 = 1.f / (dc.y + dw.y - 1.f);
            rd2 = 1.f / (dc.z + dw.z - 1.f);
            rd3 = 1.f / (dc.w + dw.w - 1.f);
            ushort4 cu = *(const ushort4*)&csin[rb + s0];
            ushort4 ru = *(const ushort4*)&rsin[rb + s0];
            f0  = (b2f(cu.x) + b2f(ru.x)) * rd0;
            f1  = (b2f(cu.y) + b2f(ru.y)) * rd1;
            f2v = (b2f(cu.z) + b2f(ru.z)) * rd2;
            f3  = (b2f(cu.w) + b2f(ru.w)) * rd3;
        }
    }
    float d4 = __shfl_down(d0, 1);
    if (lane >= 47) d4 = 0.f;

    // ---- forward scan: Z[s] = d[s]*Z[s-1] + f[s] ----
    float P = 1.f, Q = 0.f;
    if (act) {
        P = d0 * d1 * d2 * d3;
        Q = ((f0 * d1 + f1) * d2 + f2v) * d3 + f3;
    }
    #pragma unroll
    for (int off = 1; off < 64; off <<= 1) {
        float Pp = __shfl_up(P, off);
        float Qp = __shfl_up(Q, off);
        if (lane >= off) { Q = Qp * P + Q; P = Pp * P; }
    }
    float zin = __shfl_up(Q, 1);
    if (lane == 0) zin = 0.f;
    float zA = zin * d0 + f0;
    float zB = zA * d1 + f1;
    float zC = zB * d2 + f2v;
    float zD = zC * d3 + f3;

    // ---- backward scan: lanes >=48 carry identity (1,0) ----
    float Pb = 1.f, Qb = 0.f;
    if (act) {
        Pb = d4 * d3 * d2 * d1;
        Qb = ((f3 * d3 + f2v) * d2 + f1) * d1 + f0;
    }
    #pragma unroll
    for (int off = 1; off < 64; off <<= 1) {
        float Pp = __shfl_down(Pb, off);
        float Qp = __shfl_down(Qb, off);
        if (lane < 64 - off) { Qb = Qp * Pb + Qb; Pb = Pp * Pb; }
    }
    float sin_ = __shfl_down(Qb, 1);
    if (lane == 63) sin_ = 0.f;
    float sD = sin_ * d4 + f3;
    float sC = sD * d3 + f2v;
    float sB = sC * d2 + f1;
    float sA = sB * d1 + f0;

    if (act) {
        if (MODE == 2) {
            // fused final combine: out = (cs2 + rs2) * rD, fp32 coalesced
            ushort4 c2 = *(const ushort4*)&csfin[rb + s0];
            float4 o;
            o.x = (b2f(c2.x) + zA + sA - 2.f * f0)  * rd0;
            o.y = (b2f(c2.y) + zB + sB - 2.f * f1)  * rd1;
            o.z = (b2f(c2.z) + zC + sC - 2.f * f2v) * rd2;
            o.w = (b2f(c2.w) + zD + sD - 2.f * f3)  * rd3;
            *(float4*)&outg[rb + s0] = o;
        } else {
            ushort4 o;
            o.x = f2b(zA + sA - 2.f * f0);
            o.y = f2b(zB + sB - 2.f * f1);
            o.z = f2b(zC + sC - 2.f * f2v);
            o.w = f2b(zD + sD - 2.f * f3);
            *(ushort4*)&rsout[rb + s0] = o;
        }
    }

    if (MODE == 0 && c == 0) {
        // unit-f row scan -> drow = Zu + Su - 1 (fp32)
        float Pu = 1.f, Qu = 0.f;
        if (act) {
            Pu = d0 * d1 * d2 * d3;
            Qu = ((d1 + 1.f) * d2 + 1.f) * d3 + 1.f;
        }
        #pragma unroll
        for (int off = 1; off < 64; off <<= 1) {
            float Pp = __shfl_up(Pu, off);
            float Qp = __shfl_up(Qu, off);
            if (lane >= off) { Qu = Qp * Pu + Qu; Pu = Pp * Pu; }
        }
        float zuin = __shfl_up(Qu, 1);
        if (lane == 0) zuin = 0.f;
        float zuA = zuin * d0 + 1.f;
        float zuB = zuA * d1 + 1.f;
        float zuC = zuB * d2 + 1.f;
        float zuD = zuC * d3 + 1.f;

        float Pub = 1.f, Qub = 0.f;
        if (act) {
            Pub = d4 * d3 * d2 * d1;
            Qub = ((d3 + 1.f) * d2 + 1.f) * d1 + 1.f;
        }
        #pragma unroll
        for (int off = 1; off < 64; off <<= 1) {
            float Pp = __shfl_down(Pub, off);
            float Qp = __shfl_down(Qub, off);
            if (lane < 64 - off) { Qub = Qp * Pub + Qub; Pub = Pp * Pub; }
        }
        float suin = __shfl_down(Qub, 1);
        if (lane == 63) suin = 0.f;
        float suD = suin * d4 + 1.f;
        float suC = suD * d3 + 1.f;
        float suB = suC * d2 + 1.f;
        float suA = suB * d1 + 1.f;

        if (act) {
            float4 o;
            o.x = zuA + suA - 1.f;
            o.y = zuB + suB - 1.f;
            o.z = zuC + suC - 1.f;
            o.w = zuD + suD - 1.f;
            *(float4*)&drow[db + s0] = o;
        }
    }
}

// ================= L1/L2: col role + row role in one grid =================
template<int MODE>
__global__ __launch_bounds__(NTHR) void k_iter(const float* __restrict__ mask,
                                               const float* __restrict__ edge,
                                               const unsigned short* __restrict__ csin,
                                               const unsigned short* __restrict__ rsin,
                                               unsigned short* __restrict__ csout,
                                               unsigned short* __restrict__ rsout,
                                               float* __restrict__ dcol,
                                               float* __restrict__ drow) {
    const int t = threadIdx.x;
    if (blockIdx.x < NCOLB) {
        col_body<MODE>(blockIdx.x, t, mask, edge, csin, rsin, csout, dcol, drow);
    } else {
        int rblk = blockIdx.x - NCOLB;
        int wave = t >> 6, lane = t & 63;
        row_body<MODE>(rblk * 8 + wave, lane, mask, edge, csin, rsin, rsout,
                       nullptr, dcol, drow, nullptr);
    }
}

// ================= L3a: col role only (cs2) =================
__global__ __launch_bounds__(NTHR) void k_col2(const float* __restrict__ edge,
                                               const unsigned short* __restrict__ csin,
                                               const unsigned short* __restrict__ rsin,
                                               unsigned short* __restrict__ csout,
                                               const float* __restrict__ dcol,
                                               const float* __restrict__ drow) {
    col_body<1>(blockIdx.x, threadIdx.x, nullptr, edge, csin, rsin, csout,
                (float*)dcol, drow);
}

// ================= L3b: row role iter 2 + fused combine -> out =================
__global__ __launch_bounds__(NTHR) void k_rowcomb(const float* __restrict__ edge,
                                                  const unsigned short* __restrict__ csin,
                                                  const unsigned short* __restrict__ rsin,
                                                  const unsigned short* __restrict__ csfin,
                                                  const float* __restrict__ dcol,
                                                  const float* __restrict__ drow,
                                                  float* __restrict__ outg) {
    const int t = threadIdx.x;
    int wave = t >> 6, lane = t & 63;
    row_body<2>(blockIdx.x * 8 + wave, lane, nullptr, edge, csin, rsin, nullptr,
                csfin, dcol, (float*)drow, outg);
}

extern "C" void kernel_launch(void* const* d_in, const int* in_sizes, int n_in,
                              void* d_out, int out_size, void* d_ws, size_t ws_size,
                              hipStream_t stream) {
    const float* mask = (const float*)d_in[0];
    const float* edge = (const float*)d_in[1];
    float* out = (float*)d_out;

    float* dcol = (float*)d_ws;                         // [B,H,W] fp32
    float* drow = dcol + (size_t)B * HW;                // [B,H,W] fp32
    unsigned short* csA = (unsigned short*)(drow + (size_t)B * HW);
    unsigned short* rsA = csA + (size_t)NP * HW;        // bf16 [NP,H,W] each
    unsigned short* csB = rsA + (size_t)NP * HW;
    unsigned short* rsB = csB + (size_t)NP * HW;

    const int grid = NCOLB + NROWB;   // 2052

    // L1: f0 = mask -> csA, rsA (+ dcol, drow)
    k_iter<0><<<grid, NTHR, 0, stream>>>(mask, edge, nullptr, nullptr, csA, rsA, dcol, drow);
    // L2: fold A -> B
    k_iter<1><<<grid, NTHR, 0, stream>>>(nullptr, edge, csA, rsA, csB, rsB, dcol, drow);
    // L3a: col role only, fold B -> cs2 (csA)
    k_col2<<<NCOLB, NTHR, 0, stream>>>(edge, csB, rsB, csA, dcol, drow);
    // L3b: row role computes rs2 in registers + fused combine -> out
    k_rowcomb<<<NROWB, NTHR, 0, stream>>>(edge, csB, rsB, csA, dcol, drow, out);
}